// Round 16
// baseline (62.065 us; speedup 1.0000x reference)
//
#include <hip/hip_runtime.h>

constexpr float EPS_LN = 1e-5f;

using f32x4 = __attribute__((ext_vector_type(4))) float;
using s16x8 = __attribute__((ext_vector_type(8))) short;

__device__ __forceinline__ short f2bf(float f) {
  union { float f; unsigned u; } v; v.f = f;
  unsigned r = v.u + 0x7fff + ((v.u >> 16) & 1);
  return (short)(r >> 16);
}
__device__ __forceinline__ float bf2f(short h) {
  union { unsigned u; float f; } v;
  v.u = ((unsigned)(unsigned short)h) << 16;
  return v.f;
}

__device__ __forceinline__ s16x8 cvt8(float4 a, float4 b) {
  s16x8 r;
  r[0] = f2bf(a.x); r[1] = f2bf(a.y); r[2] = f2bf(a.z); r[3] = f2bf(a.w);
  r[4] = f2bf(b.x); r[5] = f2bf(b.y); r[6] = f2bf(b.z); r[7] = f2bf(b.w);
  return r;
}

#define MFMA(a, b, c) __builtin_amdgcn_mfma_f32_16x16x32_bf16((a), (b), (c), 0, 0, 0)

__device__ __forceinline__ void gld_lds16(const void* g, void* l) {
  __builtin_amdgcn_global_load_lds(
      (const __attribute__((address_space(1))) unsigned int*)g,
      (__attribute__((address_space(3))) unsigned int*)l, 16, 0, 0);
}

struct P {
  const int* uid;
  const float *qe, *le, *tab;
  const float *Wu0, *bu0, *Wq0, *bq0, *Wl0, *bl0, *g0, *be0;
  const float *Wu1, *bu1, *Wq1, *bq1, *Wl1, *bl1, *g1, *be1;
  const float *w1, *b1, *w2, *b2;
  short *wt0u, *wt0q, *wt0l, *wt1u, *wt1q, *wt1l, *w1tU, *w1tL;
  short *z0, *z1, *uqB;
  float *lw, *b1u, *b1q, *b1l, *out;
};

// Direct global->VGPR B-fragment GEMM over the chunk-sequential swizzled
// weight layout (short idx = kk*8192 + (kg*256 + col)*8 + ko). NN = 16-col
// tiles per wave. No LDS, no barriers.
template<int NK, int NN>
__device__ __forceinline__ void dgemm(const short* __restrict__ wt,
                                      const s16x8* aF, int lg, int lr, int c0,
                                      f32x4 acc[NN]) {
  #pragma unroll
  for (int kk = 0; kk < NK; ++kk) {
    const short* base = wt + (size_t)kk * 8192 + (size_t)(lg * 256 + c0 + lr) * 8;
    #pragma unroll
    for (int n = 0; n < NN; ++n) {
      const s16x8 bf = *(const s16x8*)(base + n * 128);
      acc[n] = MFMA(aF[kk], bf, acc[n]);
    }
  }
}

__device__ __forceinline__ void load_aF(const short* y_s, s16x8* aF, int lr, int lg) {
  #pragma unroll
  for (int kk = 0; kk < 8; ++kk)
    aF[kk] = *(const s16x8*)&y_s[lr * 264 + kk * 32 + lg * 8];
}

// ---- K0: transpose+cast weights (g0 folded into wt1*) + bias folds ----
// blocks 0..151: transpose; 152..163: b1X' = bX1 + be0 @ WX1.
__global__ __launch_bounds__(256) void k0_kernel(P p) {
  __shared__ float tile[64][65];
  __shared__ float red[4][64];
  int bx = blockIdx.x;
  const int tid = threadIdx.x;
  if (bx >= 152) {
    const int b = bx - 152;
    const int job = b >> 2, nq = b & 3;
    const int n = nq * 64 + (tid & 63), kp = tid >> 6;
    const float* W = (job == 0) ? p.Wu1 : (job == 1) ? p.Wq1 : p.Wl1;
    float s = 0.f;
    #pragma unroll 8
    for (int i = 0; i < 64; ++i) {
      const int k = kp * 64 + i;
      s += p.be0[k] * W[(size_t)k * 256 + n];
    }
    red[kp][tid & 63] = s;
    __syncthreads();
    if (kp == 0) {
      float t = red[0][tid] + red[1][tid] + red[2][tid] + red[3][tid];
      if (job == 0)      p.b1u[n] = t + p.bu1[n];
      else if (job == 1) p.b1q[n] = t + p.bq1[n];
      else               p.b1l[n] = t + p.bl1[n];
    }
    return;
  }
  const float* src;
  short* dst;
  const float* gv = nullptr;
  int rowoff = 0;
  if (bx < 72) {
    const int m = bx / 24; bx -= m * 24;
    src = (m == 0) ? p.Wu0 : (m == 1) ? p.Wq0 : p.Wl0;
    dst = (m == 0) ? p.wt0u : (m == 1) ? p.wt0q : p.wt0l;
  } else if (bx < 120) {
    bx -= 72; const int m = bx / 16; bx -= m * 16;
    src = (m == 0) ? p.Wu1 : (m == 1) ? p.Wq1 : p.Wl1;
    dst = (m == 0) ? p.wt1u : (m == 1) ? p.wt1q : p.wt1l;
    gv = p.g0;  // fold g0 into layer-1 weights
  } else if (bx < 136) {
    bx -= 120; src = p.w1; dst = p.w1tL;
  } else {
    bx -= 136; src = p.w1; dst = p.w1tU; rowoff = 256;
  }
  const int tn = bx & 3, tk = bx >> 2;
  {
    const int r = tid >> 2, cq = (tid & 3) * 16;
    const float* s = src + (size_t)(rowoff + tk * 64 + r) * 256 + tn * 64 + cq;
    #pragma unroll
    for (int j = 0; j < 4; ++j) {
      float4 v = *(const float4*)(s + j * 4);
      tile[r][cq + j * 4 + 0] = v.x; tile[r][cq + j * 4 + 1] = v.y;
      tile[r][cq + j * 4 + 2] = v.z; tile[r][cq + j * 4 + 3] = v.w;
    }
  }
  __syncthreads();
  {
    const int nn = tid >> 2, kq = (tid & 3) * 16;
    const int n = tn * 64 + nn;
    #pragma unroll
    for (int h = 0; h < 2; ++h) {
      const int kl = kq + h * 8;
      const int kglob = tk * 64 + kl;
      const int kk = kglob >> 5, kg = (kglob & 31) >> 3;
      s16x8 v;
      #pragma unroll
      for (int ko = 0; ko < 8; ++ko) {
        float x = tile[kl + ko][nn];
        if (gv) x *= gv[kglob + ko];
        v[ko] = f2bf(x);
      }
      *(s16x8*)(dst + ((size_t)(kk * 4 + kg) * 256 + n) * 8) = v;
    }
  }
}

// ---- G0: layer-0 GEMM, wave-tile 16 rows x 32 cols, NO LN, NO barriers.
// gw = bx*4+w in [0,4128): rowtile rt = gw>>3 (516: u 0..255, q 256..511,
// llm 512..515), cols c0 = (gw&7)*32. Stores z0 = 2*(A@W0 + b0) as bf16.
__global__ __launch_bounds__(256) void g0_kernel(P p) {
  const int tid = threadIdx.x, w = tid >> 6, lane = tid & 63;
  const int lr = lane & 15, lg = lane >> 4;
  const int gw = blockIdx.x * 4 + w;
  const int rt = gw >> 3;
  const int c0 = (gw & 7) * 32;
  const int r0 = rt * 16;
  const float* arow;
  const short* wt;
  const float* bias;
  if (rt < 256)      { arow = p.tab + (size_t)p.uid[r0 + lr] * 384; wt = p.wt0u; bias = p.bu0; }
  else if (rt < 512) { arow = p.qe + (size_t)(r0 - 4096 + lr) * 384; wt = p.wt0q; bias = p.bq0; }
  else               { arow = p.le + (size_t)(r0 - 8192 + lr) * 384; wt = p.wt0l; bias = p.bl0; }
  s16x8 aF[12];
  #pragma unroll
  for (int kk = 0; kk < 12; ++kk)
    aF[kk] = cvt8(*(const float4*)(arow + kk * 32 + lg * 8),
                  *(const float4*)(arow + kk * 32 + lg * 8 + 4));
  const f32x4 z4 = {0.f, 0.f, 0.f, 0.f};
  f32x4 acc[2] = {z4, z4};
  dgemm<12, 2>(wt, aF, lg, lr, c0, acc);
  #pragma unroll
  for (int n = 0; n < 2; ++n) {
    const int c = c0 + n * 16 + lr;
    const float bv = bias[c];
    #pragma unroll
    for (int r = 0; r < 4; ++r)
      p.z0[(size_t)(r0 + lg * 4 + r) * 256 + c] = f2bf(2.f * (acc[n][r] + bv));
  }
}

// ---- G1: layer-1 GEMM with LN-on-load (r9 pattern; g0/be0 folded into
// wt1'/b1X'). Same wave-tile mapping as G0. Stores z1 = 2*(x0hat@W1'+b1').
__global__ __launch_bounds__(256) void g1_kernel(P p) {
  const int tid = threadIdx.x, w = tid >> 6, lane = tid & 63;
  const int lr = lane & 15, lg = lane >> 4;
  const int gw = blockIdx.x * 4 + w;
  const int rt = gw >> 3;
  const int c0 = (gw & 7) * 32;
  const int r0 = rt * 16;
  const short* wt;
  const float* bias;
  if (rt < 256)      { wt = p.wt1u; bias = p.b1u; }
  else if (rt < 512) { wt = p.wt1q; bias = p.b1q; }
  else               { wt = p.wt1l; bias = p.b1l; }
  const short* zp = p.z0 + (size_t)(r0 + lr) * 256 + lg * 8;
  s16x8 raw[8];
  #pragma unroll
  for (int kk = 0; kk < 8; ++kk) raw[kk] = *(const s16x8*)(zp + kk * 32);
  float s1 = 0.f, s2 = 0.f;
  #pragma unroll
  for (int kk = 0; kk < 8; ++kk)
    #pragma unroll
    for (int j = 0; j < 8; ++j) {
      const float f = bf2f(raw[kk][j]);
      s1 += f; s2 += f * f;
    }
  s1 += __shfl_xor(s1, 16, 64); s2 += __shfl_xor(s2, 16, 64);
  s1 += __shfl_xor(s1, 32, 64); s2 += __shfl_xor(s2, 32, 64);
  const float mu = s1 * (1.f / 256.f);
  const float var = s2 * (1.f / 256.f) - mu * mu;
  const float rs = rsqrtf(var + EPS_LN);
  const float mrs = mu * rs;
  s16x8 aF[8];
  #pragma unroll
  for (int kk = 0; kk < 8; ++kk) {
    s16x8 o8;
    #pragma unroll
    for (int j = 0; j < 8; ++j) o8[j] = f2bf(bf2f(raw[kk][j]) * rs - mrs);
    aF[kk] = o8;
  }
  const f32x4 z4 = {0.f, 0.f, 0.f, 0.f};
  f32x4 acc[2] = {z4, z4};
  dgemm<8, 2>(wt, aF, lg, lr, c0, acc);
  #pragma unroll
  for (int n = 0; n < 2; ++n) {
    const int c = c0 + n * 16 + lr;
    const float bv = bias[c];
    #pragma unroll
    for (int r = 0; r < 4; ++r)
      p.z1[(size_t)(r0 + lg * 4 + r) * 256 + c] = f2bf(2.f * (acc[n][r] + bv));
  }
}

// ---- LN1: bx<256: uqB[r] = g1*(zu_hat + zq_hat) + 2*be1 (16 rows/block).
// bx 256..259: llm: y1 = g1*zl_hat + be1 -> LDS -> lw = y1 @ w1tL + b1.
__global__ __launch_bounds__(256) void ln1_kernel(P p) {
  __shared__ __align__(16) short y_s[16 * 264];
  const int tid = threadIdx.x, w = tid >> 6, lane = tid & 63;
  const int lr = lane & 15, lg = lane >> 4;
  const int bx = blockIdx.x;
  const int rloc = w * 4 + (lane >> 4);
  const int cb = (lane & 15) * 16;
  float g1a[16], be1a[16];
  #pragma unroll
  for (int q = 0; q < 4; ++q) {
    *(float4*)&g1a[q * 4]  = *(const float4*)(p.g1 + cb + q * 4);
    *(float4*)&be1a[q * 4] = *(const float4*)(p.be1 + cb + q * 4);
  }
  if (bx < 256) {
    const int r = bx * 16 + rloc;
    const short* pu = p.z1 + (size_t)r * 256 + cb;
    const short* pq = p.z1 + (size_t)(4096 + r) * 256 + cb;
    s16x8 u0 = *(const s16x8*)pu, u1 = *(const s16x8*)(pu + 8);
    s16x8 q0 = *(const s16x8*)pq, q1 = *(const s16x8*)(pq + 8);
    float su1 = 0, su2 = 0, sq1 = 0, sq2 = 0;
    #pragma unroll
    for (int j = 0; j < 8; ++j) {
      float a = bf2f(u0[j]), b = bf2f(u1[j]);
      su1 += a + b; su2 += a * a + b * b;
      float c = bf2f(q0[j]), d = bf2f(q1[j]);
      sq1 += c + d; sq2 += c * c + d * d;
    }
    #pragma unroll
    for (int off = 1; off < 16; off <<= 1) {
      su1 += __shfl_xor(su1, off, 64); su2 += __shfl_xor(su2, off, 64);
      sq1 += __shfl_xor(sq1, off, 64); sq2 += __shfl_xor(sq2, off, 64);
    }
    const float muu = su1 * (1.f / 256.f);
    const float rsu = rsqrtf(su2 * (1.f / 256.f) - muu * muu + EPS_LN);
    const float muq = sq1 * (1.f / 256.f);
    const float rsq = rsqrtf(sq2 * (1.f / 256.f) - muq * muq + EPS_LN);
    s16x8 o0, o1;
    #pragma unroll
    for (int j = 0; j < 8; ++j) {
      float nu = (bf2f(u0[j]) - muu) * rsu + (bf2f(q0[j]) - muq) * rsq;
      float nv = (bf2f(u1[j]) - muu) * rsu + (bf2f(q1[j]) - muq) * rsq;
      o0[j] = f2bf(g1a[j] * nu + 2.f * be1a[j]);
      o1[j] = f2bf(g1a[8 + j] * nv + 2.f * be1a[8 + j]);
    }
    short* op = p.uqB + (size_t)r * 256 + cb;
    *(s16x8*)op = o0;
    *(s16x8*)(op + 8) = o1;
  } else {
    const int rb = (bx - 256) * 16;
    {
      const int r = 8192 + rb + rloc;
      const short* pl = p.z1 + (size_t)r * 256 + cb;
      s16x8 l0 = *(const s16x8*)pl, l1 = *(const s16x8*)(pl + 8);
      float s1 = 0, s2 = 0;
      #pragma unroll
      for (int j = 0; j < 8; ++j) {
        float a = bf2f(l0[j]), b = bf2f(l1[j]);
        s1 += a + b; s2 += a * a + b * b;
      }
      #pragma unroll
      for (int off = 1; off < 16; off <<= 1) {
        s1 += __shfl_xor(s1, off, 64); s2 += __shfl_xor(s2, off, 64);
      }
      const float mu = s1 * (1.f / 256.f);
      const float rs = rsqrtf(s2 * (1.f / 256.f) - mu * mu + EPS_LN);
      s16x8 o0, o1;
      #pragma unroll
      for (int j = 0; j < 8; ++j) {
        o0[j] = f2bf(g1a[j] * ((bf2f(l0[j]) - mu) * rs) + be1a[j]);
        o1[j] = f2bf(g1a[8 + j] * ((bf2f(l1[j]) - mu) * rs) + be1a[8 + j]);
      }
      *(s16x8*)&y_s[rloc * 264 + cb] = o0;
      *(s16x8*)&y_s[rloc * 264 + cb + 8] = o1;
    }
    __syncthreads();
    s16x8 aH[8];
    load_aF(y_s, aH, lr, lg);
    const f32x4 z4 = {0.f, 0.f, 0.f, 0.f};
    f32x4 acc[4] = {z4, z4, z4, z4};
    const int c0 = w * 64;
    dgemm<8, 4>(p.w1tL, aH, lg, lr, c0, acc);
    #pragma unroll
    for (int n = 0; n < 4; ++n) {
      const int c = c0 + n * 16 + lr;
      const float bv = p.b1[c];
      #pragma unroll
      for (int r2 = 0; r2 < 4; ++r2)
        p.lw[(size_t)(rb + lg * 4 + r2) * 256 + c] = acc[n][r2] + bv;
    }
  }
}

// ---- kC: GEMM2 (uqB @ w1tU) in LDS + fused score -> out ----
__global__ __launch_bounds__(256, 1) void kc_kernel(P p) {
  __shared__ __align__(16) float lw_s[64 * 256];
  __shared__ __align__(16) float uqw_s[16 * 260];
  __shared__ float w2s[256];
  const int tid = threadIdx.x, w = tid >> 6, lane = tid & 63;
  const int lr = lane & 15, lg = lane >> 4;
  const int c0 = w * 64;
  const int r0 = blockIdx.x * 16;

  #pragma unroll
  for (int s = 0; s < 16; ++s) {
    const int i = w * 16 + s;
    gld_lds16(p.lw + (size_t)i * 256 + ((lane ^ (i & 7)) << 2),
              (char*)lw_s + (size_t)i * 1024);
  }
  __builtin_amdgcn_sched_barrier(0);
  w2s[tid] = p.w2[tid];

  s16x8 aF[8];
  {
    const s16x8* ap = (const s16x8*)(p.uqB + (size_t)(r0 + lr) * 256);
    #pragma unroll
    for (int kk = 0; kk < 8; ++kk) aF[kk] = ap[kk * 4 + lg];
  }
  const f32x4 z4 = {0.f, 0.f, 0.f, 0.f};
  f32x4 acc[4] = {z4, z4, z4, z4};
  dgemm<8, 4>(p.w1tU, aF, lg, lr, c0, acc);
  #pragma unroll
  for (int n = 0; n < 4; ++n)
    #pragma unroll
    for (int r = 0; r < 4; ++r)
      uqw_s[(lg * 4 + r) * 260 + c0 + n * 16 + lr] = acc[n][r];
  __syncthreads();  // drains vm (incl. lw_s global_load_lds) + lgkm

  const float b2v = p.b2[0];
  const int l = lane;
  float sacc[4] = {0.f, 0.f, 0.f, 0.f};
  #pragma unroll 4
  for (int jj = 0; jj < 64; ++jj) {
    const float4 lwv = *(const float4*)&lw_s[l * 256 + ((jj ^ (l & 7)) << 2)];
    const float4 w2v = *(const float4*)&w2s[jj * 4];
    #pragma unroll
    for (int bi = 0; bi < 4; ++bi) {
      const float4 uqv = *(const float4*)&uqw_s[(w * 4 + bi) * 260 + jj * 4];
      sacc[bi] += fmaxf(lwv.x + uqv.x, 0.f) * w2v.x;
      sacc[bi] += fmaxf(lwv.y + uqv.y, 0.f) * w2v.y;
      sacc[bi] += fmaxf(lwv.z + uqv.z, 0.f) * w2v.z;
      sacc[bi] += fmaxf(lwv.w + uqv.w, 0.f) * w2v.w;
    }
  }
  #pragma unroll
  for (int bi = 0; bi < 4; ++bi)
    p.out[(size_t)(r0 + w * 4 + bi) * 64 + l] = sacc[bi] + b2v;
}

extern "C" void kernel_launch(void* const* d_in, const int* in_sizes, int n_in,
                              void* d_out, int out_size, void* d_ws, size_t ws_size,
                              hipStream_t stream) {
  (void)in_sizes; (void)n_in; (void)out_size; (void)ws_size;
  P p;
  p.uid = (const int*)d_in[0];
  p.qe  = (const float*)d_in[1];
  p.le  = (const float*)d_in[2];
  p.tab = (const float*)d_in[3];
  p.Wu0 = (const float*)d_in[4];  p.bu0 = (const float*)d_in[5];
  p.Wq0 = (const float*)d_in[6];  p.bq0 = (const float*)d_in[7];
  p.Wl0 = (const float*)d_in[8];  p.bl0 = (const float*)d_in[9];
  p.g0  = (const float*)d_in[10]; p.be0 = (const float*)d_in[11];
  p.Wu1 = (const float*)d_in[12]; p.bu1 = (const float*)d_in[13];
  p.Wq1 = (const float*)d_in[14]; p.bq1 = (const float*)d_in[15];
  p.Wl1 = (const float*)d_in[16]; p.bl1 = (const float*)d_in[17];
  p.g1  = (const float*)d_in[18]; p.be1 = (const float*)d_in[19];
  p.w1  = (const float*)d_in[20]; p.b1  = (const float*)d_in[21];
  p.w2  = (const float*)d_in[22]; p.b2  = (const float*)d_in[23];

  short* wsS = (short*)d_ws;
  size_t o = 0;
  p.wt0u = wsS + o; o += 98304;    // 12 chunks x 8192 shorts (K=384)
  p.wt0q = wsS + o; o += 98304;
  p.wt0l = wsS + o; o += 98304;
  p.wt1u = wsS + o; o += 65536;    // 8 chunks x 8192 (g0-folded)
  p.wt1q = wsS + o; o += 65536;
  p.wt1l = wsS + o; o += 65536;
  p.w1tU = wsS + o; o += 65536;    // plain
  p.w1tL = wsS + o; o += 65536;    // plain
  p.z0   = wsS + o; o += 2113536;  // 8256x256 bf16 pre-LN z (u|q|llm)
  p.z1   = wsS + o; o += 2113536;  // 8256x256 bf16 pre-LN z1
  p.uqB  = wsS + o; o += 1048576;  // 4096x256 bf16 LN(u)+LN(q)
  float* wsF = (float*)(wsS + o);  // 16B-aligned byte offset
  p.lw  = wsF;                     // 64x256 fp32
  p.b1u = wsF + 16384;
  p.b1q = wsF + 16640;
  p.b1l = wsF + 16896;
  p.out = (float*)d_out;

  hipLaunchKernelGGL(k0_kernel, dim3(164), dim3(256), 0, stream, p);
  hipLaunchKernelGGL(g0_kernel, dim3(1032), dim3(256), 0, stream, p);
  hipLaunchKernelGGL(g1_kernel, dim3(1032), dim3(256), 0, stream, p);
  hipLaunchKernelGGL(ln1_kernel, dim3(260), dim3(256), 0, stream, p);
  hipLaunchKernelGGL(kc_kernel, dim3(256), dim3(256), 0, stream, p);
}

// Round 17
// 50.148 us; speedup vs baseline: 1.2377x; 1.2377x over previous
//
#include <hip/hip_runtime.h>

constexpr float EPS_LN = 1e-5f;

using f32x4 = __attribute__((ext_vector_type(4))) float;
using s16x8 = __attribute__((ext_vector_type(8))) short;

__device__ __forceinline__ short f2bf(float f) {
  union { float f; unsigned u; } v; v.f = f;
  unsigned r = v.u + 0x7fff + ((v.u >> 16) & 1);
  return (short)(r >> 16);
}
__device__ __forceinline__ float bf2f(short h) {
  union { unsigned u; float f; } v;
  v.u = ((unsigned)(unsigned short)h) << 16;
  return v.f;
}

// cvt8 over ext-vector f32x4 (so we can use nontemporal vector loads)
__device__ __forceinline__ s16x8 cvt8v(f32x4 a, f32x4 b) {
  s16x8 r;
  r[0] = f2bf(a[0]); r[1] = f2bf(a[1]); r[2] = f2bf(a[2]); r[3] = f2bf(a[3]);
  r[4] = f2bf(b[0]); r[5] = f2bf(b[1]); r[6] = f2bf(b[2]); r[7] = f2bf(b[3]);
  return r;
}

#define MFMA(a, b, c) __builtin_amdgcn_mfma_f32_16x16x32_bf16((a), (b), (c), 0, 0, 0)

__device__ __forceinline__ void gld_lds16(const void* g, void* l) {
  __builtin_amdgcn_global_load_lds(
      (const __attribute__((address_space(1))) unsigned int*)g,
      (__attribute__((address_space(3))) unsigned int*)l, 16, 0, 0);
}

struct P {
  const int* uid;
  const float *qe, *le, *tab;
  const float *Wu0, *bu0, *Wq0, *bq0, *Wl0, *bl0, *g0, *be0;
  const float *Wu1, *bu1, *Wq1, *bq1, *Wl1, *bl1, *g1, *be1;
  const float *w1, *b1, *w2, *b2;
  short *wt0u, *wt0q, *wt0l, *wt1u, *wt1q, *wt1l, *w1tU, *w1tL;
  short *uqU, *uqQ;
  float *lw, *out;
};

// Direct global->VGPR B-fragment GEMM over the chunk-sequential swizzled
// weight layout. Weight loads stay CACHED (the whole point: weights are the
// reused working set we want L2-resident).
template<int NK>
__device__ __forceinline__ void dgemm(const short* __restrict__ wt,
                                      const s16x8* aF, int lg, int lr, int c0,
                                      f32x4 acc[4]) {
  #pragma unroll
  for (int kk = 0; kk < NK; ++kk) {
    const short* base = wt + (size_t)kk * 8192 + (size_t)(lg * 256 + c0 + lr) * 8;
    #pragma unroll
    for (int n = 0; n < 4; ++n) {
      const s16x8 bf = *(const s16x8*)(base + n * 128);
      acc[n] = MFMA(aF[kk], bf, acc[n]);
    }
  }
}

// LayerNorm over 256 cols; in-place on z[n][r] (col=c0+n*16+lr, row=lg*4+r).
__device__ __forceinline__ void ln16(float z[4][4], int tid, int w, int lr, int lg,
                                     int c0, const float* __restrict__ g,
                                     const float* __restrict__ be,
                                     float (*ssum)[16], float (*ssq)[16],
                                     float* mub, float* rsb) {
  __syncthreads();
  float s1[4] = {0, 0, 0, 0}, s2[4] = {0, 0, 0, 0};
  #pragma unroll
  for (int n = 0; n < 4; ++n)
    #pragma unroll
    for (int r = 0; r < 4; ++r) { s1[r] += z[n][r]; s2[r] += z[n][r] * z[n][r]; }
  #pragma unroll
  for (int off = 1; off < 16; off <<= 1)
    #pragma unroll
    for (int r = 0; r < 4; ++r) {
      s1[r] += __shfl_xor(s1[r], off, 64);
      s2[r] += __shfl_xor(s2[r], off, 64);
    }
  if (lr == 0) {
    #pragma unroll
    for (int r = 0; r < 4; ++r) { ssum[w][lg * 4 + r] = s1[r]; ssq[w][lg * 4 + r] = s2[r]; }
  }
  __syncthreads();
  if (tid < 16) {
    float S1 = 0, S2 = 0;
    #pragma unroll
    for (int ww = 0; ww < 4; ++ww) { S1 += ssum[ww][tid]; S2 += ssq[ww][tid]; }
    float mu = S1 * (1.f / 256.f);
    float var = S2 * (1.f / 256.f) - mu * mu;
    mub[tid] = mu;
    rsb[tid] = rsqrtf(var + EPS_LN);
  }
  __syncthreads();
  #pragma unroll
  for (int n = 0; n < 4; ++n) {
    const int c = c0 + n * 16 + lr;
    const float gv = g[c], bv = be[c];
    #pragma unroll
    for (int r = 0; r < 4; ++r) {
      const int rr = lg * 4 + r;
      z[n][r] = gv * (z[n][r] - mub[rr]) * rsb[rr] + bv;
    }
  }
}

__device__ __forceinline__ void bias2(const f32x4 acc[4], const float* __restrict__ b,
                                      int c0, int lr, float z[4][4]) {
  #pragma unroll
  for (int n = 0; n < 4; ++n) {
    const float bv = b[c0 + n * 16 + lr];
    #pragma unroll
    for (int r = 0; r < 4; ++r) z[n][r] = 2.f * (acc[n][r] + bv);
  }
}

__device__ __forceinline__ void store_y(const float z[4][4], short* y_s,
                                        int c0, int lr, int lg) {
  #pragma unroll
  for (int n = 0; n < 4; ++n)
    #pragma unroll
    for (int r = 0; r < 4; ++r)
      y_s[(lg * 4 + r) * 264 + c0 + n * 16 + lr] = f2bf(z[n][r]);
}

__device__ __forceinline__ void load_aF(const short* y_s, s16x8* aF, int lr, int lg) {
  #pragma unroll
  for (int kk = 0; kk < 8; ++kk)
    aF[kk] = *(const s16x8*)&y_s[lr * 264 + kk * 32 + lg * 8];
}

// ---- K0: tiled transpose+cast into the CHUNK-SEQUENTIAL swizzled layout ----
// Source fp32 weights read NONTEMPORAL (read-once); bf16 dest stays cached
// (it IS the reused working set for kab/kc).
__global__ __launch_bounds__(256) void k0_kernel(P p) {
  __shared__ float tile[64][65];
  int bx = blockIdx.x;
  const int tid = threadIdx.x;
  const float* src;
  short* dst;
  int rowoff = 0;
  if (bx < 72) {
    const int m = bx / 24; bx -= m * 24;
    src = (m == 0) ? p.Wu0 : (m == 1) ? p.Wq0 : p.Wl0;
    dst = (m == 0) ? p.wt0u : (m == 1) ? p.wt0q : p.wt0l;
  } else if (bx < 120) {
    bx -= 72; const int m = bx / 16; bx -= m * 16;
    src = (m == 0) ? p.Wu1 : (m == 1) ? p.Wq1 : p.Wl1;
    dst = (m == 0) ? p.wt1u : (m == 1) ? p.wt1q : p.wt1l;
  } else if (bx < 136) {
    bx -= 120; src = p.w1; dst = p.w1tL;
  } else {
    bx -= 136; src = p.w1; dst = p.w1tU; rowoff = 256;
  }
  const int tn = bx & 3, tk = bx >> 2;
  {
    const int r = tid >> 2, cq = (tid & 3) * 16;
    const float* s = src + (size_t)(rowoff + tk * 64 + r) * 256 + tn * 64 + cq;
    #pragma unroll
    for (int j = 0; j < 4; ++j) {
      f32x4 v = __builtin_nontemporal_load((const f32x4*)(s + j * 4));
      tile[r][cq + j * 4 + 0] = v[0]; tile[r][cq + j * 4 + 1] = v[1];
      tile[r][cq + j * 4 + 2] = v[2]; tile[r][cq + j * 4 + 3] = v[3];
    }
  }
  __syncthreads();
  {
    const int nn = tid >> 2, kq = (tid & 3) * 16;
    const int n = tn * 64 + nn;
    #pragma unroll
    for (int h = 0; h < 2; ++h) {
      const int kl = kq + h * 8;
      const int kglob = tk * 64 + kl;
      const int kk = kglob >> 5, kg = (kglob & 31) >> 3;
      s16x8 v;
      #pragma unroll
      for (int ko = 0; ko < 8; ++ko) v[ko] = f2bf(tile[kl + ko][nn]);
      *(s16x8*)(dst + ((size_t)(kk * 4 + kg) * 256 + n) * 8) = v;
    }
  }
}

// ---- kAB: full per-path chain, intermediate via LDS (r13 structure).
// STREAMING traffic (table/qe/le reads, uqU/uqQ writes) is NONTEMPORAL so it
// doesn't evict the 1.2MB weight working set from each XCD's L2.
// bx 0..255: u rows bx*16 -> uqU ; 256..511: q -> uqQ ; 512..515: llm -> lw.
__global__ __launch_bounds__(256) void kab_kernel(P p) {
  __shared__ __align__(16) short y_s[16 * 264];
  __shared__ float ssum[4][16], ssq[4][16], mub[16], rsb[16];
  const int tid = threadIdx.x, w = tid >> 6, lane = tid & 63;
  const int lr = lane & 15, lg = lane >> 4;
  const int c0 = w * 64;
  const int bx = blockIdx.x;
  const f32x4 z4 = {0.f, 0.f, 0.f, 0.f};

  if (bx < 512) {
    const bool isq = bx >= 256;
    const int t = bx & 255;
    const int r0 = t * 16;
    const float* arow = isq ? p.qe + (size_t)(r0 + lr) * 384
                            : p.tab + (size_t)p.uid[r0 + lr] * 384;
    const short* wt0 = isq ? p.wt0q : p.wt0u;
    const float* b0  = isq ? p.bq0 : p.bu0;
    const short* wt1 = isq ? p.wt1q : p.wt1u;
    const float* b1v = isq ? p.bq1 : p.bu1;
    short* outB      = isq ? p.uqQ : p.uqU;

    s16x8 aF[12];
    #pragma unroll
    for (int kk = 0; kk < 12; ++kk)
      aF[kk] = cvt8v(
          __builtin_nontemporal_load((const f32x4*)(arow + kk * 32 + lg * 8)),
          __builtin_nontemporal_load((const f32x4*)(arow + kk * 32 + lg * 8 + 4)));
    f32x4 acc[4] = {z4, z4, z4, z4};
    dgemm<12>(wt0, aF, lg, lr, c0, acc);
    float z[4][4];
    bias2(acc, b0, c0, lr, z);
    ln16(z, tid, w, lr, lg, c0, p.g0, p.be0, ssum, ssq, mub, rsb);
    store_y(z, y_s, c0, lr, lg);
    __syncthreads();
    s16x8 aH[8];
    load_aF(y_s, aH, lr, lg);
    #pragma unroll
    for (int n = 0; n < 4; ++n) acc[n] = z4;
    dgemm<8>(wt1, aH, lg, lr, c0, acc);
    bias2(acc, b1v, c0, lr, z);
    ln16(z, tid, w, lr, lg, c0, p.g1, p.be1, ssum, ssq, mub, rsb);
    store_y(z, y_s, c0, lr, lg);
    __syncthreads();
    #pragma unroll
    for (int i = 0; i < 2; ++i) {
      const int idx = i * 256 + tid;
      const int row = idx >> 5, cc = (idx & 31) * 8;
      __builtin_nontemporal_store(*(const s16x8*)&y_s[row * 264 + cc],
                                  (s16x8*)(outB + (size_t)(r0 + row) * 256 + cc));
    }
  } else {
    const int rb = (bx - 512) * 16;
    const float* arow = p.le + (size_t)(rb + lr) * 384;
    s16x8 aF[12];
    #pragma unroll
    for (int kk = 0; kk < 12; ++kk)
      aF[kk] = cvt8v(
          __builtin_nontemporal_load((const f32x4*)(arow + kk * 32 + lg * 8)),
          __builtin_nontemporal_load((const f32x4*)(arow + kk * 32 + lg * 8 + 4)));
    f32x4 acc[4] = {z4, z4, z4, z4};
    dgemm<12>(p.wt0l, aF, lg, lr, c0, acc);
    float z[4][4];
    bias2(acc, p.bl0, c0, lr, z);
    ln16(z, tid, w, lr, lg, c0, p.g0, p.be0, ssum, ssq, mub, rsb);
    store_y(z, y_s, c0, lr, lg);
    __syncthreads();
    s16x8 aH[8];
    load_aF(y_s, aH, lr, lg);
    #pragma unroll
    for (int n = 0; n < 4; ++n) acc[n] = z4;
    dgemm<8>(p.wt1l, aH, lg, lr, c0, acc);
    bias2(acc, p.bl1, c0, lr, z);
    ln16(z, tid, w, lr, lg, c0, p.g1, p.be1, ssum, ssq, mub, rsb);
    store_y(z, y_s, c0, lr, lg);
    __syncthreads();
    load_aF(y_s, aH, lr, lg);
    #pragma unroll
    for (int n = 0; n < 4; ++n) acc[n] = z4;
    dgemm<8>(p.w1tL, aH, lg, lr, c0, acc);
    // lw stays CACHED: kc re-reads it 256x
    #pragma unroll
    for (int n = 0; n < 4; ++n) {
      const int c = c0 + n * 16 + lr;
      const float bv = p.b1[c];
      #pragma unroll
      for (int r = 0; r < 4; ++r)
        p.lw[(size_t)(rb + lg * 4 + r) * 256 + c] = acc[n][r] + bv;
    }
  }
}

// ---- kC: GEMM2 (A = uqU+uqQ on load, NT reads) + fused score -> out ----
__global__ __launch_bounds__(256, 1) void kc_kernel(P p) {
  __shared__ __align__(16) float lw_s[64 * 256];
  __shared__ __align__(16) float uqw_s[16 * 260];
  __shared__ float w2s[256];
  const int tid = threadIdx.x, w = tid >> 6, lane = tid & 63;
  const int lr = lane & 15, lg = lane >> 4;
  const int c0 = w * 64;
  const int r0 = blockIdx.x * 16;

  #pragma unroll
  for (int s = 0; s < 16; ++s) {
    const int i = w * 16 + s;
    gld_lds16(p.lw + (size_t)i * 256 + ((lane ^ (i & 7)) << 2),
              (char*)lw_s + (size_t)i * 1024);
  }
  __builtin_amdgcn_sched_barrier(0);
  w2s[tid] = p.w2[tid];

  s16x8 aF[8];
  {
    const s16x8* pu = (const s16x8*)(p.uqU + (size_t)(r0 + lr) * 256);
    const s16x8* pq = (const s16x8*)(p.uqQ + (size_t)(r0 + lr) * 256);
    #pragma unroll
    for (int kk = 0; kk < 8; ++kk) {
      const s16x8 a = __builtin_nontemporal_load(pu + kk * 4 + lg);
      const s16x8 b = __builtin_nontemporal_load(pq + kk * 4 + lg);
      s16x8 o;
      #pragma unroll
      for (int j = 0; j < 8; ++j) o[j] = f2bf(bf2f(a[j]) + bf2f(b[j]));
      aF[kk] = o;
    }
  }
  const f32x4 z4 = {0.f, 0.f, 0.f, 0.f};
  f32x4 acc[4] = {z4, z4, z4, z4};
  dgemm<8>(p.w1tU, aF, lg, lr, c0, acc);
  #pragma unroll
  for (int n = 0; n < 4; ++n)
    #pragma unroll
    for (int r = 0; r < 4; ++r)
      uqw_s[(lg * 4 + r) * 260 + c0 + n * 16 + lr] = acc[n][r];
  __syncthreads();  // drains vm (incl. lw_s global_load_lds) + lgkm

  const float b2v = p.b2[0];
  const int l = lane;
  float sacc[4] = {0.f, 0.f, 0.f, 0.f};
  #pragma unroll 4
  for (int jj = 0; jj < 64; ++jj) {
    const float4 lwv = *(const float4*)&lw_s[l * 256 + ((jj ^ (l & 7)) << 2)];
    const float4 w2v = *(const float4*)&w2s[jj * 4];
    #pragma unroll
    for (int bi = 0; bi < 4; ++bi) {
      const float4 uqv = *(const float4*)&uqw_s[(w * 4 + bi) * 260 + jj * 4];
      sacc[bi] += fmaxf(lwv.x + uqv.x, 0.f) * w2v.x;
      sacc[bi] += fmaxf(lwv.y + uqv.y, 0.f) * w2v.y;
      sacc[bi] += fmaxf(lwv.z + uqv.z, 0.f) * w2v.z;
      sacc[bi] += fmaxf(lwv.w + uqv.w, 0.f) * w2v.w;
    }
  }
  #pragma unroll
  for (int bi = 0; bi < 4; ++bi)
    __builtin_nontemporal_store(sacc[bi] + b2v,
                                p.out + (size_t)(r0 + w * 4 + bi) * 64 + l);
}

extern "C" void kernel_launch(void* const* d_in, const int* in_sizes, int n_in,
                              void* d_out, int out_size, void* d_ws, size_t ws_size,
                              hipStream_t stream) {
  (void)in_sizes; (void)n_in; (void)out_size; (void)ws_size;
  P p;
  p.uid = (const int*)d_in[0];
  p.qe  = (const float*)d_in[1];
  p.le  = (const float*)d_in[2];
  p.tab = (const float*)d_in[3];
  p.Wu0 = (const float*)d_in[4];  p.bu0 = (const float*)d_in[5];
  p.Wq0 = (const float*)d_in[6];  p.bq0 = (const float*)d_in[7];
  p.Wl0 = (const float*)d_in[8];  p.bl0 = (const float*)d_in[9];
  p.g0  = (const float*)d_in[10]; p.be0 = (const float*)d_in[11];
  p.Wu1 = (const float*)d_in[12]; p.bu1 = (const float*)d_in[13];
  p.Wq1 = (const float*)d_in[14]; p.bq1 = (const float*)d_in[15];
  p.Wl1 = (const float*)d_in[16]; p.bl1 = (const float*)d_in[17];
  p.g1  = (const float*)d_in[18]; p.be1 = (const float*)d_in[19];
  p.w1  = (const float*)d_in[20]; p.b1  = (const float*)d_in[21];
  p.w2  = (const float*)d_in[22]; p.b2  = (const float*)d_in[23];

  short* wsS = (short*)d_ws;
  size_t o = 0;
  p.wt0u = wsS + o; o += 98304;    // 12 chunks x 8192 shorts (K=384)
  p.wt0q = wsS + o; o += 98304;
  p.wt0l = wsS + o; o += 98304;
  p.wt1u = wsS + o; o += 65536;    // 8 chunks x 8192 (K=256)
  p.wt1q = wsS + o; o += 65536;
  p.wt1l = wsS + o; o += 65536;
  p.w1tU = wsS + o; o += 65536;    // w1[256:512] swizzled
  p.w1tL = wsS + o; o += 65536;    // w1[0:256] swizzled
  p.uqU  = wsS + o; o += 1048576;  // 4096x256 bf16 normalized u1
  p.uqQ  = wsS + o; o += 1048576;  // 4096x256 bf16 normalized q1
  p.lw   = (float*)(wsS + o);      // 64x256 fp32 (16B-aligned byte offset)
  p.out  = (float*)d_out;

  hipLaunchKernelGGL(k0_kernel, dim3(152), dim3(256), 0, stream, p);
  hipLaunchKernelGGL(kab_kernel, dim3(516), dim3(256), 0, stream, p);
  hipLaunchKernelGGL(kc_kernel, dim3(256), dim3(256), 0, stream, p);
}